// Round 10
// baseline (126.209 us; speedup 1.0000x reference)
//
#include <hip/hip_runtime.h>
#include <hip/hip_bf16.h>
#include <cstddef>
#include <cstdint>

#define B_ 8
#define H_ 8
#define N_ 512
#define K_ 16
#define NN_ (N_*N_)

static constexpr float ALPHA_C = 0.001f;

typedef float f32x4 __attribute__((ext_vector_type(4)));

#define LDSTRIDE 20   // floats per LDS row: 16 + 4 pad, keeps 16B alignment

// -------------------------------------------------------------------------
// Strip matmul helpers (expm): one wave owns one 16x16 matrix.
//   lane -> row r = lane>>2, col strip c0 = 4*(lane&3).
// -------------------------------------------------------------------------
__device__ __forceinline__ void mm_rowB(const float* a, const float* Bbuf,
                                        int c0, f32x4& acc)
{
    #pragma unroll
    for (int k = 0; k < 16; ++k) {
        const f32x4 bk = *(const f32x4*)&Bbuf[k * LDSTRIDE + c0];
        acc.x = fmaf(a[k], bk.x, acc.x);
        acc.y = fmaf(a[k], bk.y, acc.y);
        acc.z = fmaf(a[k], bk.z, acc.z);
        acc.w = fmaf(a[k], bk.w, acc.w);
    }
}

__device__ __forceinline__ void read_row(const float* buf, int r, float* a)
{
    #pragma unroll
    for (int i = 0; i < 4; ++i) {
        const f32x4 t = *(const f32x4*)&buf[r * LDSTRIDE + 4 * i];
        a[4*i]   = t.x; a[4*i+1] = t.y; a[4*i+2] = t.z; a[4*i+3] = t.w;
    }
}

__device__ __forceinline__ void write_strip(float* buf, int r, int c0, f32x4 s)
{
    *(f32x4*)&buf[r * LDSTRIDE + c0] = s;
}

// -------------------------------------------------------------------------
// Kernel 1 (v10): expm + HALF-beta (h = 0..3). Structure = R8's proven
// staged kernel but with only 8 beta loads (bt[8] = 32 regs, strictly
// lighter): issue 8-load burst, run prologue + A2 + A3 (latency cover),
// fold, store 4-head PARTIAL SUMS to bavg (k2 adds its half and /8).
// Demand-rate halved: 33.5 MB over the kernel vs 67 MB -> the expm chain
// (~5.6 us chip-time) now covers a comparable beta share. Emits Om, v, q,
// bavg(partial h0..3).
// -------------------------------------------------------------------------
__global__ __launch_bounds__(256) void expm_beta_kernel(
    const float* __restrict__ mu, const float* __restrict__ phi,
    const float* __restrict__ gen, const float* __restrict__ beta,
    float* __restrict__ Om, float* __restrict__ v, float* __restrict__ q,
    float* __restrict__ bavg)
{
    __shared__ float lds[4][2][16 * LDSTRIDE];

    const int tid  = threadIdx.x;
    const int w    = tid >> 6, lane = tid & 63;
    const int r    = lane >> 2, c0 = (lane & 3) << 2;
    const int bn   = (blockIdx.x << 2) | w;
    const int bb   = bn >> 9;            // batch index
    const int nn   = bn & 511;           // row index

    float* U0 = lds[w][0];
    float* U1 = lds[w][1];

    // --- issue expm inputs (oldest in vmcnt) ---
    const float p0 = phi[bn*3+0], p1 = phi[bn*3+1], p2 = phi[bn*3+2];
    const int gidx = r * 16 + c0;
    const f32x4 g0 = *(const f32x4*)&gen[gidx];
    const f32x4 g1 = *(const f32x4*)&gen[256 + gidx];
    const f32x4 g2 = *(const f32x4*)&gen[512 + gidx];
    const float mur = mu[bn * 16 + r];

    // --- issue HALF beta burst: h = 0..3, both j-halves (8 loads) ---
    const size_t betaBase = (((size_t)bb * H_) * N_ + nn) * N_;
    const float* bp = beta + betaBase + (lane << 2);
    f32x4 bt[8];
    #pragma unroll
    for (int h = 0; h < 4; ++h) {
        bt[2*h+0] = __builtin_nontemporal_load((const f32x4*)(bp + (size_t)h * NN_));
        bt[2*h+1] = __builtin_nontemporal_load((const f32x4*)(bp + (size_t)h * NN_ + 256));
    }

    // --- prologue (waits only on phi/gen: counted vmcnt) ---
    f32x4 As;
    As.x = p0*g0.x + p1*g1.x + p2*g2.x;
    As.y = p0*g0.y + p1*g1.y + p2*g2.y;
    As.z = p0*g0.z + p1*g1.z + p2*g2.z;
    As.w = p0*g0.w + p1*g1.w + p2*g2.w;

    float t = As.x*As.x + As.y*As.y + As.z*As.z + As.w*As.w;
    #pragma unroll
    for (int m = 1; m <= 32; m <<= 1) t += __shfl_xor(t, m, 64);
    float theta = sqrtf(t);
    int s = 0;
    while (theta > 2.0f && s < 30) { theta *= 0.5f; ++s; }
    const float sc = exp2f((float)(-s));
    const f32x4 Xs = As * sc;

    write_strip(U0, r, c0, Xs);
    float xrow[16];
    read_row(U0, r, xrow);

    // A2 = X*X
    f32x4 a2s = {0.f, 0.f, 0.f, 0.f};
    mm_rowB(xrow, U0, c0, a2s);
    write_strip(U1, r, c0, a2s);

    // A3 = X*A2
    f32x4 a3s = {0.f, 0.f, 0.f, 0.f};
    mm_rowB(xrow, U1, c0, a3s);

    // --- fold half-beta (bt dies), store PARTIAL sums (no /8) ---
    {
        const f32x4 s0 = (bt[0] + bt[2]) + (bt[4] + bt[6]);
        const f32x4 s1 = (bt[1] + bt[3]) + (bt[5] + bt[7]);
        float* bo = bavg + (size_t)bn * N_ + (lane << 2);
        *(f32x4*)bo         = s0;
        *(f32x4*)(bo + 256) = s1;
    }

    // A4 = A2*A2
    float a2row[16];
    read_row(U1, r, a2row);
    f32x4 a4s = {0.f, 0.f, 0.f, 0.f};
    mm_rowB(a2row, U1, c0, a4s);
    write_strip(U0, r, c0, a4s);
    float a4row[16];
    read_row(U0, r, a4row);

    f32x4 di = {0.f, 0.f, 0.f, 0.f};
    if (r >= c0 && r < c0 + 4) ((float*)&di)[r - c0] = 1.0f;

    const f32x4 C0 = di + Xs + a2s * 0.5f + a3s * (1.0f/6.0f);
    const f32x4 C1 = di * (1.0f/24.0f) + Xs * (1.0f/120.0f)
                   + a2s * (1.0f/720.0f) + a3s * (1.0f/5040.0f);
    const f32x4 Q2 = di * (1.0f/40320.0f) + Xs * (1.0f/362880.0f)
                   + a2s * (1.0f/3628800.0f) + a3s * (1.0f/39916800.0f)
                   + a4s * (1.0f/479001600.0f);

    // T1 = C1 + A4*Q2
    write_strip(U1, r, c0, Q2);
    f32x4 T1 = C1;
    mm_rowB(a4row, U1, c0, T1);

    // P = C0 + A4*T1
    write_strip(U1, r, c0, T1);
    f32x4 P = C0;
    mm_rowB(a4row, U1, c0, P);

    // s squarings (wave-uniform; no barriers)
    for (int it = 0; it < s; ++it) {
        write_strip(U1, r, c0, P);
        float prow[16];
        read_row(U1, r, prow);
        f32x4 Pn = {0.f, 0.f, 0.f, 0.f};
        mm_rowB(prow, U1, c0, Pn);
        P = Pn;
    }

    *(f32x4*)&Om[(size_t)bn * 256 + r * 16 + c0] = P;

    f32x4 vc = P * mur;
    #pragma unroll
    for (int m = 4; m <= 32; m <<= 1) {
        vc.x += __shfl_xor(vc.x, m, 64);
        vc.y += __shfl_xor(vc.y, m, 64);
        vc.z += __shfl_xor(vc.z, m, 64);
        vc.w += __shfl_xor(vc.w, m, 64);
    }
    if (r == 0) *(f32x4*)&v[bn * 16 + c0] = vc;

    float qp = vc.x*vc.x + vc.y*vc.y + vc.z*vc.z + vc.w*vc.w;
    qp += __shfl_xor(qp, 1, 64);
    qp += __shfl_xor(qp, 2, 64);
    if (lane == 0) q[bn] = 0.5f * qp;
}

// -------------------------------------------------------------------------
// Reduction helpers for grad (register arrays, fully unrolled -> static idx).
// -------------------------------------------------------------------------
__device__ __forceinline__ float fold16(float* wc, int lane)
{
    #pragma unroll
    for (int k = 0; k < 8; ++k) {             // mask 32, keep 8
        const bool up = (lane & 32) != 0;
        const float send = up ? wc[k] : wc[k + 8];
        const float recv = __shfl_xor(send, 32, 64);
        wc[k] = (up ? wc[k + 8] : wc[k]) + recv;
    }
    #pragma unroll
    for (int k = 0; k < 4; ++k) {             // mask 16, keep 4
        const bool up = (lane & 16) != 0;
        const float send = up ? wc[k] : wc[k + 4];
        const float recv = __shfl_xor(send, 16, 64);
        wc[k] = (up ? wc[k + 4] : wc[k]) + recv;
    }
    #pragma unroll
    for (int k = 0; k < 2; ++k) {             // mask 8, keep 2
        const bool up = (lane & 8) != 0;
        const float send = up ? wc[k] : wc[k + 2];
        const float recv = __shfl_xor(send, 8, 64);
        wc[k] = (up ? wc[k + 2] : wc[k]) + recv;
    }
    {                                          // mask 4, keep 1
        const bool up = (lane & 4) != 0;
        const float send = up ? wc[0] : wc[1];
        const float recv = __shfl_xor(send, 4, 64);
        wc[0] = (up ? wc[1] : wc[0]) + recv;
    }
    wc[0] += __shfl_xor(wc[0], 2, 64);
    wc[0] += __shfl_xor(wc[0], 1, 64);
    return wc[0];
}

__device__ __forceinline__ float rot_reduce(const float* omr, float gv, int lane)
{
    float pr[4];
    #pragma unroll
    for (int rr = 0; rr < 4; ++rr) pr[rr] = omr[rr] * gv;

    #pragma unroll
    for (int k = 0; k < 2; ++k) {             // mask 4, keep 2
        const bool up = (lane & 4) != 0;
        const float send = up ? pr[k] : pr[k + 2];
        const float recv = __shfl_xor(send, 4, 64);
        pr[k] = (up ? pr[k + 2] : pr[k]) + recv;
    }
    {                                          // mask 8, keep 1
        const bool up = (lane & 8) != 0;
        const float send = up ? pr[0] : pr[1];
        const float recv = __shfl_xor(send, 8, 64);
        pr[0] = (up ? pr[1] : pr[0]) + recv;
    }
    pr[0] += __shfl_xor(pr[0], 16, 64);
    pr[0] += __shfl_xor(pr[0], 32, 64);
    return pr[0];
}

// -------------------------------------------------------------------------
// Kernel 2 (v10): R5's 2-row combined-coefficient grad + INLINE half-beta
// (h = 4..7 for both rows, 16 loads). Register law: at the scatter peak,
// live = tq 32 + bt 64 + addr ~10 = ~106 < 128 cap at (256,2). The k1
// partial-bavg loads are issued AFTER the barrier so they never coexist
// with the burst. bt dies at the fold; w-pass peak ~111 (proven clean R5).
// -------------------------------------------------------------------------
__global__ __launch_bounds__(256, 2) void grad_kernel(
    const float* __restrict__ mu, const float* __restrict__ beta,
    const float* __restrict__ mu_prior, const float* __restrict__ lrp,
    const float* __restrict__ Om, const float* __restrict__ v,
    const float* __restrict__ q, const float* __restrict__ bavg,
    float* __restrict__ out)
{
    __shared__ float v_t[16 * 516];      // 16 rows x 129 float4 (pad 1 f4)
    __shared__ f32x4 q4[128];

    const int blk = blockIdx.x;          // 0..511
    const int b   = blk >> 6;
    const int i0  = (blk & 63) << 3;
    const int tid = threadIdx.x;
    const int wid = tid >> 6, lane = tid & 63;
    const int ia  = i0 + wid;
    const int ib  = i0 + 4 + wid;
    const size_t rowia = (size_t)b * N_ + ia;
    const size_t rowib = (size_t)b * N_ + ib;

    // ---- 1. v staging + q (oldest in vmcnt) ----
    const float* vb = v + (size_t)b * N_ * K_;
    f32x4 tq[8];
    #pragma unroll
    for (int s = 0; s < 8; ++s)
        tq[s] = *(const f32x4*)&vb[(tid + 256 * s) << 2];

    f32x4 qreg = {0.f, 0.f, 0.f, 0.f};
    const f32x4* qb4 = (const f32x4*)(q + (size_t)b * N_);
    if (tid < 128) qreg = qb4[tid];

    // ---- 2. half-beta burst: h = 4..7 for BOTH rows (16 loads) ----
    const float* bA = beta + ((size_t)b * H_ * N_ + ia) * N_ + (lane << 2);
    const float* bB = beta + ((size_t)b * H_ * N_ + ib) * N_ + (lane << 2);
    f32x4 bt[16];
    #pragma unroll
    for (int h = 4; h < 8; ++h) {
        bt[2*(h-4)+0] = __builtin_nontemporal_load((const f32x4*)(bA + (size_t)h * NN_));
        bt[2*(h-4)+1] = __builtin_nontemporal_load((const f32x4*)(bA + (size_t)h * NN_ + 256));
        bt[2*(h-4)+8] = __builtin_nontemporal_load((const f32x4*)(bB + (size_t)h * NN_));
        bt[2*(h-4)+9] = __builtin_nontemporal_load((const f32x4*)(bB + (size_t)h * NN_ + 256));
    }

    // ---- 3. LDS scatter of staged v (waits tq only; beta in flight) ----
    #pragma unroll
    for (int s = 0; s < 8; ++s) {
        const int f4 = tid + 256 * s;
        const int j  = f4 >> 2;
        const int k0 = (f4 & 3) << 2;
        v_t[(k0+0) * 516 + j] = tq[s].x;
        v_t[(k0+1) * 516 + j] = tq[s].y;
        v_t[(k0+2) * 516 + j] = tq[s].z;
        v_t[(k0+3) * 516 + j] = tq[s].w;
    }
    if (tid < 128) q4[tid] = qreg;
    __syncthreads();

    // ---- 4. k1 partials (issued post-barrier; L2/L3-hot), fold beta ----
    const float* bpa = bavg + rowia * N_ + (lane << 2);
    const float* bpb = bavg + rowib * N_ + (lane << 2);
    const f32x4 pA0 = *(const f32x4*)bpa;
    const f32x4 pA1 = *(const f32x4*)(bpa + 256);
    const f32x4 pB0 = *(const f32x4*)bpb;
    const f32x4 pB1 = *(const f32x4*)(bpb + 256);

    const f32x4 rvA0 = (pA0 + ((bt[0] + bt[2]) + (bt[4] + bt[6])))  * 0.125f;
    const f32x4 rvA1 = (pA1 + ((bt[1] + bt[3]) + (bt[5] + bt[7])))  * 0.125f;
    const f32x4 rvB0 = (pB0 + ((bt[8] + bt[10]) + (bt[12] + bt[14]))) * 0.125f;
    const f32x4 rvB1 = (pB1 + ((bt[9] + bt[11]) + (bt[13] + bt[15]))) * 0.125f;

    // ---- 5. vi for both rows; d-pass (each vj read -> 8 fma) ----
    float via[16], vib[16];
    #pragma unroll
    for (int k = 0; k < 16; ++k) { via[k] = v_t[k * 516 + ia]; vib[k] = v_t[k * 516 + ib]; }
    const float qia = ((const float*)q4)[ia];
    const float qib = ((const float*)q4)[ib];

    const int j0 = lane << 2;

    float dAa0=0.f,dAa1=0.f,dAa2=0.f,dAa3=0.f, dAb0=0.f,dAb1=0.f,dAb2=0.f,dAb3=0.f;
    #pragma unroll
    for (int k = 0; k < 16; ++k) {
        const f32x4 vj = *(const f32x4*)&v_t[k * 516 + j0];
        dAa0 = fmaf(via[k], vj.x, dAa0);
        dAa1 = fmaf(via[k], vj.y, dAa1);
        dAa2 = fmaf(via[k], vj.z, dAa2);
        dAa3 = fmaf(via[k], vj.w, dAa3);
        dAb0 = fmaf(vib[k], vj.x, dAb0);
        dAb1 = fmaf(vib[k], vj.y, dAb1);
        dAb2 = fmaf(vib[k], vj.z, dAb2);
        dAb3 = fmaf(vib[k], vj.w, dAb3);
    }
    float dBa0=0.f,dBa1=0.f,dBa2=0.f,dBa3=0.f, dBb0=0.f,dBb1=0.f,dBb2=0.f,dBb3=0.f;
    #pragma unroll
    for (int k = 0; k < 16; ++k) {
        const f32x4 vj = *(const f32x4*)&v_t[k * 516 + j0 + 256];
        dBa0 = fmaf(via[k], vj.x, dBa0);
        dBa1 = fmaf(via[k], vj.y, dBa1);
        dBa2 = fmaf(via[k], vj.z, dBa2);
        dBa3 = fmaf(via[k], vj.w, dBa3);
        dBb0 = fmaf(vib[k], vj.x, dBb0);
        dBb1 = fmaf(vib[k], vj.y, dBb1);
        dBb2 = fmaf(vib[k], vj.z, dBb2);
        dBb3 = fmaf(vib[k], vj.w, dBb3);
    }

    // ---- 6. rkl for both rows, both halves (via/vib die here) ----
    const f32x4 qjA = q4[lane];
    const f32x4 qjB = q4[lane | 64];

    const float rklAa0 = rvA0.x * (qia + qjA.x - dAa0);
    const float rklAa1 = rvA0.y * (qia + qjA.y - dAa1);
    const float rklAa2 = rvA0.z * (qia + qjA.z - dAa2);
    const float rklAa3 = rvA0.w * (qia + qjA.w - dAa3);
    const float rklBa0 = rvA1.x * (qia + qjB.x - dBa0);
    const float rklBa1 = rvA1.y * (qia + qjB.y - dBa1);
    const float rklBa2 = rvA1.z * (qia + qjB.z - dBa2);
    const float rklBa3 = rvA1.w * (qia + qjB.w - dBa3);

    const float rklAb0 = rvB0.x * (qib + qjA.x - dAb0);
    const float rklAb1 = rvB0.y * (qib + qjA.y - dAb1);
    const float rklAb2 = rvB0.z * (qib + qjA.z - dAb2);
    const float rklAb3 = rvB0.w * (qib + qjA.w - dAb3);
    const float rklBb0 = rvB1.x * (qib + qjB.x - dBb0);
    const float rklBb1 = rvB1.y * (qib + qjB.y - dBb1);
    const float rklBb2 = rvB1.z * (qib + qjB.z - dBb2);
    const float rklBb3 = rvB1.w * (qib + qjB.w - dBb3);

    float sacc_a = ((rklAa0 + rklAa1) + (rklAa2 + rklAa3))
                 + ((rklBa0 + rklBa1) + (rklBa2 + rklBa3));
    float sacc_b = ((rklAb0 + rklAb1) + (rklAb2 + rklAb3))
                 + ((rklBb0 + rklBb1) + (rklBb2 + rklBb3));
    float R_a = ((rvA0.x + rvA0.y) + (rvA0.z + rvA0.w))
              + ((rvA1.x + rvA1.y) + (rvA1.z + rvA1.w));
    float R_b = ((rvB0.x + rvB0.y) + (rvB0.z + rvB0.w))
              + ((rvB1.x + rvB1.y) + (rvB1.z + rvB1.w));

    // ---- 7. epilogue loads issued here; latency drains under butterfly ----
    const int cmine = (lane >> 2) & 15;
    const int tqi   = lane & 3;
    const float* omba = Om + rowia * 256;
    const float* ombb = Om + rowib * 256;
    float omra[4], omrb[4];
    #pragma unroll
    for (int rr = 0; rr < 4; ++rr) {
        omra[rr] = omba[(4 * tqi + rr) * 16 + cmine];
        omrb[rr] = ombb[(4 * tqi + rr) * 16 + cmine];
    }
    const int row = 4 * tqi + 2 * ((lane >> 2) & 1) + ((lane >> 3) & 1);
    const size_t oia = rowia * 16 + row;
    const size_t oib = rowib * 16 + row;
    float m0a = 0.f, mpa = 0.f, m0b = 0.f, mpb = 0.f;
    if (lane < 16) {
        m0a = mu[oia]; mpa = mu_prior[oia];
        m0b = mu[oib]; mpb = mu_prior[oib];
    }
    const float lrv = lrp[0];

    // ---- 8. butterfly all 4 scalars (oms needed BEFORE w-pass) ----
    #pragma unroll
    for (int off = 32; off > 0; off >>= 1) {
        sacc_a += __shfl_xor(sacc_a, off, 64);
        R_a    += __shfl_xor(R_a,    off, 64);
        sacc_b += __shfl_xor(sacc_b, off, 64);
        R_b    += __shfl_xor(R_b,    off, 64);
    }
    const float oms_a  = 1.0f - sacc_a;
    const float coef_a = oms_a * R_a + sacc_a;
    const float oms_b  = 1.0f - sacc_b;
    const float coef_b = oms_b * R_b + sacc_b;

    // ---- 9. combined coefficients c = oms*rv + rkl ----
    const float cAa0 = fmaf(oms_a, rvA0.x, rklAa0);
    const float cAa1 = fmaf(oms_a, rvA0.y, rklAa1);
    const float cAa2 = fmaf(oms_a, rvA0.z, rklAa2);
    const float cAa3 = fmaf(oms_a, rvA0.w, rklAa3);
    const float cBa0 = fmaf(oms_a, rvA1.x, rklBa0);
    const float cBa1 = fmaf(oms_a, rvA1.y, rklBa1);
    const float cBa2 = fmaf(oms_a, rvA1.z, rklBa2);
    const float cBa3 = fmaf(oms_a, rvA1.w, rklBa3);
    const float cAb0 = fmaf(oms_b, rvB0.x, rklAb0);
    const float cAb1 = fmaf(oms_b, rvB0.y, rklAb1);
    const float cAb2 = fmaf(oms_b, rvB0.z, rklAb2);
    const float cAb3 = fmaf(oms_b, rvB0.w, rklAb3);
    const float cBb0 = fmaf(oms_b, rvB1.x, rklBb0);
    const float cBb1 = fmaf(oms_b, rvB1.y, rklBb1);
    const float cBb2 = fmaf(oms_b, rvB1.z, rklBb2);
    const float cBb3 = fmaf(oms_b, rvB1.w, rklBb3);

    // ---- 10. w-pass: ONE accumulator set per row (8 fma per vj read) ----
    float wca[16], wcb[16];
    #pragma unroll
    for (int k = 0; k < 16; ++k) { wca[k] = 0.f; wcb[k] = 0.f; }

    #pragma unroll
    for (int k = 0; k < 16; ++k) {
        const f32x4 vj = *(const f32x4*)&v_t[k * 516 + j0];
        float t1 = fmaf(cAa0, vj.x, wca[k]);
        t1 = fmaf(cAa1, vj.y, t1);
        t1 = fmaf(cAa2, vj.z, t1);
        wca[k] = fmaf(cAa3, vj.w, t1);
        float t2 = fmaf(cAb0, vj.x, wcb[k]);
        t2 = fmaf(cAb1, vj.y, t2);
        t2 = fmaf(cAb2, vj.z, t2);
        wcb[k] = fmaf(cAb3, vj.w, t2);
    }
    #pragma unroll
    for (int k = 0; k < 16; ++k) {
        const f32x4 vj = *(const f32x4*)&v_t[k * 516 + j0 + 256];
        float t1 = fmaf(cBa0, vj.x, wca[k]);
        t1 = fmaf(cBa1, vj.y, t1);
        t1 = fmaf(cBa2, vj.z, t1);
        wca[k] = fmaf(cBa3, vj.w, t1);
        float t2 = fmaf(cBb0, vj.x, wcb[k]);
        t2 = fmaf(cBb1, vj.y, t2);
        t2 = fmaf(cBb2, vj.z, t2);
        wcb[k] = fmaf(cBb3, vj.w, t2);
    }

    // ---- 11. fold + rotate + write ----
    const float wfa = fold16(wca, lane);
    const float wfb = fold16(wcb, lane);

    const float gva = coef_a * v_t[cmine * 516 + ia] - wfa;
    const float gvb = coef_b * v_t[cmine * 516 + ib] - wfb;
    const float pra = rot_reduce(omra, gva, lane);
    const float prb = rot_reduce(omrb, gvb, lane);

    if (lane < 16) {
        out[oia] = m0a - lrv * (ALPHA_C * (m0a - mpa) + pra);
        out[oib] = m0b - lrv * (ALPHA_C * (m0b - mpb) + prb);
    }
}

// -------------------------------------------------------------------------
extern "C" void kernel_launch(void* const* d_in, const int* in_sizes, int n_in,
                              void* d_out, int out_size, void* d_ws, size_t ws_size,
                              hipStream_t stream)
{
    const float* mu   = (const float*)d_in[0];
    const float* beta = (const float*)d_in[1];
    const float* mup  = (const float*)d_in[2];
    const float* phi  = (const float*)d_in[3];
    const float* gen  = (const float*)d_in[4];
    const float* lr   = (const float*)d_in[5];
    float* out = (float*)d_out;

    float* Om   = (float*)d_ws;                     // 4096*256 floats = 4 MB
    float* v    = Om + (size_t)4096 * 256;          // 4096*16
    float* q    = v  + (size_t)4096 * 16;           // 4096
    float* bavg = q  + (size_t)4096;                // 8*512*512 = 8 MB (partial)

    expm_beta_kernel<<<B_ * N_ / 4, 256, 0, stream>>>(mu, phi, gen, beta, Om, v, q, bavg);
    grad_kernel<<<B_ * (N_ / 8), 256, 0, stream>>>(mu, beta, mup, lr, Om, v, q, bavg, out);
}

// Round 11
// 110.355 us; speedup vs baseline: 1.1437x; 1.1437x over previous
//
#include <hip/hip_runtime.h>
#include <hip/hip_bf16.h>
#include <cstddef>
#include <cstdint>

#define B_ 8
#define H_ 8
#define N_ 512
#define K_ 16
#define NN_ (N_*N_)

static constexpr float ALPHA_C = 0.001f;

typedef float f32x4 __attribute__((ext_vector_type(4)));

#define LDSTRIDE 20   // floats per LDS row: 16 + 4 pad, keeps 16B alignment

// -------------------------------------------------------------------------
// Strip matmul helpers (expm): one wave owns one 16x16 matrix.
//   lane -> row r = lane>>2, col strip c0 = 4*(lane&3).
// -------------------------------------------------------------------------
__device__ __forceinline__ void mm_rowB(const float* a, const float* Bbuf,
                                        int c0, f32x4& acc)
{
    #pragma unroll
    for (int k = 0; k < 16; ++k) {
        const f32x4 bk = *(const f32x4*)&Bbuf[k * LDSTRIDE + c0];
        acc.x = fmaf(a[k], bk.x, acc.x);
        acc.y = fmaf(a[k], bk.y, acc.y);
        acc.z = fmaf(a[k], bk.z, acc.z);
        acc.w = fmaf(a[k], bk.w, acc.w);
    }
}

__device__ __forceinline__ void read_row(const float* buf, int r, float* a)
{
    #pragma unroll
    for (int i = 0; i < 4; ++i) {
        const f32x4 t = *(const f32x4*)&buf[r * LDSTRIDE + 4 * i];
        a[4*i]   = t.x; a[4*i+1] = t.y; a[4*i+2] = t.z; a[4*i+3] = t.w;
    }
}

__device__ __forceinline__ void write_strip(float* buf, int r, int c0, f32x4 s)
{
    *(f32x4*)&buf[r * LDSTRIDE + c0] = s;
}

// -------------------------------------------------------------------------
// Kernel 1 (v11): R8's staged-fold expm+beta kernel, byte-identical EXCEPT
// the 16 beta loads are PLAIN f32x4 loads (was __builtin_nontemporal_load).
// A/B hypothesis H3: the NT flag routes around L2 onto a streaming path
// that caps at ~2.7 TB/s on gfx950 -- the one constant across all five
// schedules whose beta phase never beat 2.6-2.7 TB/s, while plain-path
// references (fills, float4-copy ubench) hit 6.3-6.4 TB/s.
// -------------------------------------------------------------------------
__global__ __launch_bounds__(256) void expm_beta_kernel(
    const float* __restrict__ mu, const float* __restrict__ phi,
    const float* __restrict__ gen, const float* __restrict__ beta,
    float* __restrict__ Om, float* __restrict__ v, float* __restrict__ q,
    float* __restrict__ bavg)
{
    __shared__ float lds[4][2][16 * LDSTRIDE];

    const int tid  = threadIdx.x;
    const int w    = tid >> 6, lane = tid & 63;
    const int r    = lane >> 2, c0 = (lane & 3) << 2;
    const int bn   = (blockIdx.x << 2) | w;
    const int bb   = bn >> 9;            // batch index
    const int nn   = bn & 511;           // row index

    float* U0 = lds[w][0];
    float* U1 = lds[w][1];

    // --- issue expm inputs (oldest in vmcnt) ---
    const float p0 = phi[bn*3+0], p1 = phi[bn*3+1], p2 = phi[bn*3+2];
    const int gidx = r * 16 + c0;
    const f32x4 g0 = *(const f32x4*)&gen[gidx];
    const f32x4 g1 = *(const f32x4*)&gen[256 + gidx];
    const f32x4 g2 = *(const f32x4*)&gen[512 + gidx];
    const float mur = mu[bn * 16 + r];

    // --- issue the full beta burst (16 PLAIN loads, 1 KB/lane) ---
    const size_t betaBase = (((size_t)bb * H_) * N_ + nn) * N_;
    const float* bp = beta + betaBase + (lane << 2);
    f32x4 bt[16];
    #pragma unroll
    for (int h = 0; h < H_; ++h) {
        bt[2*h+0] = *(const f32x4*)(bp + (size_t)h * NN_);
        bt[2*h+1] = *(const f32x4*)(bp + (size_t)h * NN_ + 256);
    }

    // --- prologue (waits only on phi/gen: counted vmcnt) ---
    f32x4 As;
    As.x = p0*g0.x + p1*g1.x + p2*g2.x;
    As.y = p0*g0.y + p1*g1.y + p2*g2.y;
    As.z = p0*g0.z + p1*g1.z + p2*g2.z;
    As.w = p0*g0.w + p1*g1.w + p2*g2.w;

    float t = As.x*As.x + As.y*As.y + As.z*As.z + As.w*As.w;
    #pragma unroll
    for (int m = 1; m <= 32; m <<= 1) t += __shfl_xor(t, m, 64);
    float theta = sqrtf(t);
    int s = 0;
    while (theta > 2.0f && s < 30) { theta *= 0.5f; ++s; }
    const float sc = exp2f((float)(-s));
    const f32x4 Xs = As * sc;

    write_strip(U0, r, c0, Xs);
    float xrow[16];
    read_row(U0, r, xrow);

    // A2 = X*X
    f32x4 a2s = {0.f, 0.f, 0.f, 0.f};
    mm_rowB(xrow, U0, c0, a2s);
    write_strip(U1, r, c0, a2s);

    // A3 = X*A2
    f32x4 a3s = {0.f, 0.f, 0.f, 0.f};
    mm_rowB(xrow, U1, c0, a3s);

    // --- STAGE-A fold: bt[0..7] (h=0..3); counted vmcnt, 2 matmuls done ---
    f32x4 pa0 = (bt[0] + bt[2]) + (bt[4] + bt[6]);
    f32x4 pa1 = (bt[1] + bt[3]) + (bt[5] + bt[7]);

    // A4 = A2*A2
    float a2row[16];
    read_row(U1, r, a2row);
    f32x4 a4s = {0.f, 0.f, 0.f, 0.f};
    mm_rowB(a2row, U1, c0, a4s);
    write_strip(U0, r, c0, a4s);
    float a4row[16];
    read_row(U0, r, a4row);

    f32x4 di = {0.f, 0.f, 0.f, 0.f};
    if (r >= c0 && r < c0 + 4) ((float*)&di)[r - c0] = 1.0f;

    const f32x4 C0 = di + Xs + a2s * 0.5f + a3s * (1.0f/6.0f);
    const f32x4 C1 = di * (1.0f/24.0f) + Xs * (1.0f/120.0f)
                   + a2s * (1.0f/720.0f) + a3s * (1.0f/5040.0f);
    const f32x4 Q2 = di * (1.0f/40320.0f) + Xs * (1.0f/362880.0f)
                   + a2s * (1.0f/3628800.0f) + a3s * (1.0f/39916800.0f)
                   + a4s * (1.0f/479001600.0f);

    // T1 = C1 + A4*Q2
    write_strip(U1, r, c0, Q2);
    f32x4 T1 = C1;
    mm_rowB(a4row, U1, c0, T1);

    // --- STAGE-B fold: bt[8..15] (h=4..7); ~4 matmuls executed. Store. ---
    {
        const f32x4 rv0 = (pa0 + ((bt[8]+bt[10]) + (bt[12]+bt[14]))) * 0.125f;
        const f32x4 rv1 = (pa1 + ((bt[9]+bt[11]) + (bt[13]+bt[15]))) * 0.125f;
        float* bo = bavg + (size_t)bn * N_ + (lane << 2);
        *(f32x4*)bo         = rv0;
        *(f32x4*)(bo + 256) = rv1;
    }

    // P = C0 + A4*T1
    write_strip(U1, r, c0, T1);
    f32x4 P = C0;
    mm_rowB(a4row, U1, c0, P);

    // s squarings (wave-uniform; no barriers)
    for (int it = 0; it < s; ++it) {
        write_strip(U1, r, c0, P);
        float prow[16];
        read_row(U1, r, prow);
        f32x4 Pn = {0.f, 0.f, 0.f, 0.f};
        mm_rowB(prow, U1, c0, Pn);
        P = Pn;
    }

    *(f32x4*)&Om[(size_t)bn * 256 + r * 16 + c0] = P;

    f32x4 vc = P * mur;
    #pragma unroll
    for (int m = 4; m <= 32; m <<= 1) {
        vc.x += __shfl_xor(vc.x, m, 64);
        vc.y += __shfl_xor(vc.y, m, 64);
        vc.z += __shfl_xor(vc.z, m, 64);
        vc.w += __shfl_xor(vc.w, m, 64);
    }
    if (r == 0) *(f32x4*)&v[bn * 16 + c0] = vc;

    float qp = vc.x*vc.x + vc.y*vc.y + vc.z*vc.z + vc.w*vc.w;
    qp += __shfl_xor(qp, 1, 64);
    qp += __shfl_xor(qp, 2, 64);
    if (lane == 0) q[bn] = 0.5f * qp;
}

// -------------------------------------------------------------------------
// Reduction helpers for grad (register arrays, fully unrolled -> static idx).
// -------------------------------------------------------------------------
__device__ __forceinline__ float fold16(float* wc, int lane)
{
    #pragma unroll
    for (int k = 0; k < 8; ++k) {             // mask 32, keep 8
        const bool up = (lane & 32) != 0;
        const float send = up ? wc[k] : wc[k + 8];
        const float recv = __shfl_xor(send, 32, 64);
        wc[k] = (up ? wc[k + 8] : wc[k]) + recv;
    }
    #pragma unroll
    for (int k = 0; k < 4; ++k) {             // mask 16, keep 4
        const bool up = (lane & 16) != 0;
        const float send = up ? wc[k] : wc[k + 4];
        const float recv = __shfl_xor(send, 16, 64);
        wc[k] = (up ? wc[k + 4] : wc[k]) + recv;
    }
    #pragma unroll
    for (int k = 0; k < 2; ++k) {             // mask 8, keep 2
        const bool up = (lane & 8) != 0;
        const float send = up ? wc[k] : wc[k + 2];
        const float recv = __shfl_xor(send, 8, 64);
        wc[k] = (up ? wc[k + 2] : wc[k]) + recv;
    }
    {                                          // mask 4, keep 1
        const bool up = (lane & 4) != 0;
        const float send = up ? wc[0] : wc[1];
        const float recv = __shfl_xor(send, 4, 64);
        wc[0] = (up ? wc[1] : wc[0]) + recv;
    }
    wc[0] += __shfl_xor(wc[0], 2, 64);
    wc[0] += __shfl_xor(wc[0], 1, 64);
    return wc[0];
}

__device__ __forceinline__ float rot_reduce(const float* omr, float gv, int lane)
{
    float pr[4];
    #pragma unroll
    for (int rr = 0; rr < 4; ++rr) pr[rr] = omr[rr] * gv;

    #pragma unroll
    for (int k = 0; k < 2; ++k) {             // mask 4, keep 2
        const bool up = (lane & 4) != 0;
        const float send = up ? pr[k] : pr[k + 2];
        const float recv = __shfl_xor(send, 4, 64);
        pr[k] = (up ? pr[k + 2] : pr[k]) + recv;
    }
    {                                          // mask 8, keep 1
        const bool up = (lane & 8) != 0;
        const float send = up ? pr[0] : pr[1];
        const float recv = __shfl_xor(send, 8, 64);
        pr[0] = (up ? pr[1] : pr[0]) + recv;
    }
    pr[0] += __shfl_xor(pr[0], 16, 64);
    pr[0] += __shfl_xor(pr[0], 32, 64);
    return pr[0];
}

// -------------------------------------------------------------------------
// Kernel 2: R5's grad v5, BYTE-IDENTICAL (verified clean, ~8 us).
// 2-row wave, combined-coefficient w-pass; __launch_bounds__(256,2) ->
// cap 128, peak demand ~111, no spill.
// -------------------------------------------------------------------------
__global__ __launch_bounds__(256, 2) void grad_kernel(
    const float* __restrict__ mu, const float* __restrict__ mu_prior,
    const float* __restrict__ lrp, const float* __restrict__ Om,
    const float* __restrict__ v, const float* __restrict__ q,
    const float* __restrict__ bavg, float* __restrict__ out)
{
    __shared__ float v_t[16 * 516];      // 16 rows x 129 float4 (pad 1 f4)
    __shared__ f32x4 q4[128];

    const int blk = blockIdx.x;          // 0..511
    const int b   = blk >> 6;
    const int i0  = (blk & 63) << 3;
    const int tid = threadIdx.x;
    const int wid = tid >> 6, lane = tid & 63;
    const int ia  = i0 + wid;
    const int ib  = i0 + 4 + wid;
    const size_t rowia = (size_t)b * N_ + ia;
    const size_t rowib = (size_t)b * N_ + ib;

    // ---- 1. issue v staging + q + bavg ----
    const float* vb = v + (size_t)b * N_ * K_;
    f32x4 tq[8];
    #pragma unroll
    for (int s = 0; s < 8; ++s)
        tq[s] = *(const f32x4*)&vb[(tid + 256 * s) << 2];

    f32x4 qreg = {0.f, 0.f, 0.f, 0.f};
    const f32x4* qb4 = (const f32x4*)(q + (size_t)b * N_);
    if (tid < 128) qreg = qb4[tid];

    const float* bpa = bavg + rowia * N_ + (lane << 2);
    const float* bpb = bavg + rowib * N_ + (lane << 2);
    const f32x4 rvA0 = *(const f32x4*)bpa;
    const f32x4 rvA1 = *(const f32x4*)(bpa + 256);
    const f32x4 rvB0 = *(const f32x4*)bpb;
    const f32x4 rvB1 = *(const f32x4*)(bpb + 256);

    // ---- 2. LDS scatter of staged v (transposed) ----
    #pragma unroll
    for (int s = 0; s < 8; ++s) {
        const int f4 = tid + 256 * s;
        const int j  = f4 >> 2;
        const int k0 = (f4 & 3) << 2;
        v_t[(k0+0) * 516 + j] = tq[s].x;
        v_t[(k0+1) * 516 + j] = tq[s].y;
        v_t[(k0+2) * 516 + j] = tq[s].z;
        v_t[(k0+3) * 516 + j] = tq[s].w;
    }
    if (tid < 128) q4[tid] = qreg;
    __syncthreads();

    // ---- 3. vi for both rows; d-pass (each vj read -> 8 fma) ----
    float via[16], vib[16];
    #pragma unroll
    for (int k = 0; k < 16; ++k) { via[k] = v_t[k * 516 + ia]; vib[k] = v_t[k * 516 + ib]; }
    const float qia = ((const float*)q4)[ia];
    const float qib = ((const float*)q4)[ib];

    const int j0 = lane << 2;

    float dAa0=0.f,dAa1=0.f,dAa2=0.f,dAa3=0.f, dAb0=0.f,dAb1=0.f,dAb2=0.f,dAb3=0.f;
    #pragma unroll
    for (int k = 0; k < 16; ++k) {
        const f32x4 vj = *(const f32x4*)&v_t[k * 516 + j0];
        dAa0 = fmaf(via[k], vj.x, dAa0);
        dAa1 = fmaf(via[k], vj.y, dAa1);
        dAa2 = fmaf(via[k], vj.z, dAa2);
        dAa3 = fmaf(via[k], vj.w, dAa3);
        dAb0 = fmaf(vib[k], vj.x, dAb0);
        dAb1 = fmaf(vib[k], vj.y, dAb1);
        dAb2 = fmaf(vib[k], vj.z, dAb2);
        dAb3 = fmaf(vib[k], vj.w, dAb3);
    }
    float dBa0=0.f,dBa1=0.f,dBa2=0.f,dBa3=0.f, dBb0=0.f,dBb1=0.f,dBb2=0.f,dBb3=0.f;
    #pragma unroll
    for (int k = 0; k < 16; ++k) {
        const f32x4 vj = *(const f32x4*)&v_t[k * 516 + j0 + 256];
        dBa0 = fmaf(via[k], vj.x, dBa0);
        dBa1 = fmaf(via[k], vj.y, dBa1);
        dBa2 = fmaf(via[k], vj.z, dBa2);
        dBa3 = fmaf(via[k], vj.w, dBa3);
        dBb0 = fmaf(vib[k], vj.x, dBb0);
        dBb1 = fmaf(vib[k], vj.y, dBb1);
        dBb2 = fmaf(vib[k], vj.z, dBb2);
        dBb3 = fmaf(vib[k], vj.w, dBb3);
    }

    // ---- 4. rkl for both rows, both halves (via/vib die here) ----
    const f32x4 qjA = q4[lane];
    const f32x4 qjB = q4[lane | 64];

    const float rklAa0 = rvA0.x * (qia + qjA.x - dAa0);
    const float rklAa1 = rvA0.y * (qia + qjA.y - dAa1);
    const float rklAa2 = rvA0.z * (qia + qjA.z - dAa2);
    const float rklAa3 = rvA0.w * (qia + qjA.w - dAa3);
    const float rklBa0 = rvA1.x * (qia + qjB.x - dBa0);
    const float rklBa1 = rvA1.y * (qia + qjB.y - dBa1);
    const float rklBa2 = rvA1.z * (qia + qjB.z - dBa2);
    const float rklBa3 = rvA1.w * (qia + qjB.w - dBa3);

    const float rklAb0 = rvB0.x * (qib + qjA.x - dAb0);
    const float rklAb1 = rvB0.y * (qib + qjA.y - dAb1);
    const float rklAb2 = rvB0.z * (qib + qjA.z - dAb2);
    const float rklAb3 = rvB0.w * (qib + qjA.w - dAb3);
    const float rklBb0 = rvB1.x * (qib + qjB.x - dBb0);
    const float rklBb1 = rvB1.y * (qib + qjB.y - dBb1);
    const float rklBb2 = rvB1.z * (qib + qjB.z - dBb2);
    const float rklBb3 = rvB1.w * (qib + qjB.w - dBb3);

    float sacc_a = ((rklAa0 + rklAa1) + (rklAa2 + rklAa3))
                 + ((rklBa0 + rklBa1) + (rklBa2 + rklBa3));
    float sacc_b = ((rklAb0 + rklAb1) + (rklAb2 + rklAb3))
                 + ((rklBb0 + rklBb1) + (rklBb2 + rklBb3));
    float R_a = ((rvA0.x + rvA0.y) + (rvA0.z + rvA0.w))
              + ((rvA1.x + rvA1.y) + (rvA1.z + rvA1.w));
    float R_b = ((rvB0.x + rvB0.y) + (rvB0.z + rvB0.w))
              + ((rvB1.x + rvB1.y) + (rvB1.z + rvB1.w));

    // ---- 5. epilogue loads issued here; latency drains under butterfly ----
    const int cmine = (lane >> 2) & 15;
    const int tqi   = lane & 3;
    const float* omba = Om + rowia * 256;
    const float* ombb = Om + rowib * 256;
    float omra[4], omrb[4];
    #pragma unroll
    for (int rr = 0; rr < 4; ++rr) {
        omra[rr] = omba[(4 * tqi + rr) * 16 + cmine];
        omrb[rr] = ombb[(4 * tqi + rr) * 16 + cmine];
    }
    const int row = 4 * tqi + 2 * ((lane >> 2) & 1) + ((lane >> 3) & 1);
    const size_t oia = rowia * 16 + row;
    const size_t oib = rowib * 16 + row;
    float m0a = 0.f, mpa = 0.f, m0b = 0.f, mpb = 0.f;
    if (lane < 16) {
        m0a = mu[oia]; mpa = mu_prior[oia];
        m0b = mu[oib]; mpb = mu_prior[oib];
    }
    const float lrv = lrp[0];

    // ---- 6. butterfly all 4 scalars (oms needed BEFORE w-pass) ----
    #pragma unroll
    for (int off = 32; off > 0; off >>= 1) {
        sacc_a += __shfl_xor(sacc_a, off, 64);
        R_a    += __shfl_xor(R_a,    off, 64);
        sacc_b += __shfl_xor(sacc_b, off, 64);
        R_b    += __shfl_xor(R_b,    off, 64);
    }
    const float oms_a  = 1.0f - sacc_a;
    const float coef_a = oms_a * R_a + sacc_a;
    const float oms_b  = 1.0f - sacc_b;
    const float coef_b = oms_b * R_b + sacc_b;

    // ---- 7. combined coefficients c = oms*rv + rkl ----
    const float cAa0 = fmaf(oms_a, rvA0.x, rklAa0);
    const float cAa1 = fmaf(oms_a, rvA0.y, rklAa1);
    const float cAa2 = fmaf(oms_a, rvA0.z, rklAa2);
    const float cAa3 = fmaf(oms_a, rvA0.w, rklAa3);
    const float cBa0 = fmaf(oms_a, rvA1.x, rklBa0);
    const float cBa1 = fmaf(oms_a, rvA1.y, rklBa1);
    const float cBa2 = fmaf(oms_a, rvA1.z, rklBa2);
    const float cBa3 = fmaf(oms_a, rvA1.w, rklBa3);
    const float cAb0 = fmaf(oms_b, rvB0.x, rklAb0);
    const float cAb1 = fmaf(oms_b, rvB0.y, rklAb1);
    const float cAb2 = fmaf(oms_b, rvB0.z, rklAb2);
    const float cAb3 = fmaf(oms_b, rvB0.w, rklAb3);
    const float cBb0 = fmaf(oms_b, rvB1.x, rklBb0);
    const float cBb1 = fmaf(oms_b, rvB1.y, rklBb1);
    const float cBb2 = fmaf(oms_b, rvB1.z, rklBb2);
    const float cBb3 = fmaf(oms_b, rvB1.w, rklBb3);

    // ---- 8. w-pass: ONE accumulator set per row (8 fma per vj read) ----
    float wca[16], wcb[16];
    #pragma unroll
    for (int k = 0; k < 16; ++k) { wca[k] = 0.f; wcb[k] = 0.f; }

    #pragma unroll
    for (int k = 0; k < 16; ++k) {
        const f32x4 vj = *(const f32x4*)&v_t[k * 516 + j0];
        float t1 = fmaf(cAa0, vj.x, wca[k]);
        t1 = fmaf(cAa1, vj.y, t1);
        t1 = fmaf(cAa2, vj.z, t1);
        wca[k] = fmaf(cAa3, vj.w, t1);
        float t2 = fmaf(cAb0, vj.x, wcb[k]);
        t2 = fmaf(cAb1, vj.y, t2);
        t2 = fmaf(cAb2, vj.z, t2);
        wcb[k] = fmaf(cAb3, vj.w, t2);
    }
    #pragma unroll
    for (int k = 0; k < 16; ++k) {
        const f32x4 vj = *(const f32x4*)&v_t[k * 516 + j0 + 256];
        float t1 = fmaf(cBa0, vj.x, wca[k]);
        t1 = fmaf(cBa1, vj.y, t1);
        t1 = fmaf(cBa2, vj.z, t1);
        wca[k] = fmaf(cBa3, vj.w, t1);
        float t2 = fmaf(cBb0, vj.x, wcb[k]);
        t2 = fmaf(cBb1, vj.y, t2);
        t2 = fmaf(cBb2, vj.z, t2);
        wcb[k] = fmaf(cBb3, vj.w, t2);
    }

    // ---- 9. fold + rotate + write ----
    const float wfa = fold16(wca, lane);
    const float wfb = fold16(wcb, lane);

    const float gva = coef_a * v_t[cmine * 516 + ia] - wfa;
    const float gvb = coef_b * v_t[cmine * 516 + ib] - wfb;
    const float pra = rot_reduce(omra, gva, lane);
    const float prb = rot_reduce(omrb, gvb, lane);

    if (lane < 16) {
        out[oia] = m0a - lrv * (ALPHA_C * (m0a - mpa) + pra);
        out[oib] = m0b - lrv * (ALPHA_C * (m0b - mpb) + prb);
    }
}

// -------------------------------------------------------------------------
extern "C" void kernel_launch(void* const* d_in, const int* in_sizes, int n_in,
                              void* d_out, int out_size, void* d_ws, size_t ws_size,
                              hipStream_t stream)
{
    const float* mu   = (const float*)d_in[0];
    const float* beta = (const float*)d_in[1];
    const float* mup  = (const float*)d_in[2];
    const float* phi  = (const float*)d_in[3];
    const float* gen  = (const float*)d_in[4];
    const float* lr   = (const float*)d_in[5];
    float* out = (float*)d_out;

    float* Om   = (float*)d_ws;                     // 4096*256 floats = 4 MB
    float* v    = Om + (size_t)4096 * 256;          // 4096*16
    float* q    = v  + (size_t)4096 * 16;           // 4096
    float* bavg = q  + (size_t)4096;                // 8*512*512 = 8 MB

    expm_beta_kernel<<<B_ * N_ / 4, 256, 0, stream>>>(mu, phi, gen, beta, Om, v, q, bavg);
    grad_kernel<<<B_ * (N_ / 8), 256, 0, stream>>>(mu, mup, lr, Om, v, q, bavg, out);
}